// Round 1
// baseline (238.023 us; speedup 1.0000x reference)
//
#include <hip/hip_runtime.h>

#define S_LEN 1024
#define BATCH 4

typedef unsigned short u16;
using bf16x8 = __attribute__((ext_vector_type(8))) short;
using f32x4  = __attribute__((ext_vector_type(4))) float;
using u16x8  = __attribute__((ext_vector_type(8))) unsigned short;
using u16x4  = __attribute__((ext_vector_type(4))) unsigned short;

__device__ __forceinline__ float bf2f(u16 b) {
  unsigned int u = ((unsigned int)b) << 16;
  return __builtin_bit_cast(float, u);
}
__device__ __forceinline__ u16 f2bf(float f) {
  unsigned int u = __builtin_bit_cast(unsigned int, f);
  unsigned int r = u + 0x7fffu + ((u >> 16) & 1u);
  return (u16)(r >> 16);
}

using gas_p = const __attribute__((address_space(1))) void*;
using las_p = __attribute__((address_space(3))) void*;

__device__ __forceinline__ void gload16(const void* g, void* l) {
  __builtin_amdgcn_global_load_lds((gas_p)g, (las_p)l, 16, 0, 0);
}

// ---------------- f32 -> bf16 conversion ----------------
__global__ __launch_bounds__(256) void cvt_bf16(const float* __restrict__ in,
                                                u16* __restrict__ out, int n) {
  int i = (blockIdx.x * 256 + threadIdx.x) * 4;
  if (i >= n) return;
  float4 v = *(const float4*)(in + i);
  u16x4 o;
  o.x = f2bf(v.x); o.y = f2bf(v.y); o.z = f2bf(v.z); o.w = f2bf(v.w);
  *(u16x4*)(out + i) = o;
}

// ---------------- qc = q+u, qp = q+v ----------------
__global__ __launch_bounds__(256) void make_qcqp(const u16* __restrict__ qkv,
    const float* __restrict__ uvec, const float* __restrict__ vvec,
    u16* __restrict__ qc, u16* __restrict__ qp) {
  size_t i8 = ((size_t)blockIdx.x * 256 + threadIdx.x) * 8;
  int row = (int)(i8 >> 10);
  int col = (int)(i8 & 1023);
  u16x8 qv = *(const u16x8*)(qkv + (size_t)row * 3072 + col);
  u16x8 oc, op;
#pragma unroll
  for (int j = 0; j < 8; ++j) {
    float q = bf2f(qv[j]);
    oc[j] = f2bf(q + uvec[col + j]);
    op[j] = f2bf(q + vvec[col + j]);
  }
  *(u16x8*)(qc + i8) = oc;
  *(u16x8*)(qp + i8) = op;
}

// ---------------- GEMM: Y = A @ W^T  (A[M,K], W[N,K] both bf16 row-major) ----------------
template <int OUTF32>
__global__ __launch_bounds__(256) void gemm_bt(const u16* __restrict__ A,
    const u16* __restrict__ W, float* __restrict__ Yf, u16* __restrict__ Yb,
    int M, int N, int K) {
  __shared__ u16 As[128 * 32];
  __shared__ u16 Ws[128 * 32];
  const int t = threadIdx.x;
  const int w = t >> 6, l = t & 63;
  const int lr = l & 15, lg = l >> 4;
  const int bm = blockIdx.x, bn = blockIdx.y;
  const int wr = (w >> 1) * 64, wc = (w & 1) * 64;
  f32x4 acc[4][4];
#pragma unroll
  for (int mi = 0; mi < 4; ++mi)
#pragma unroll
    for (int ni = 0; ni < 4; ++ni) acc[mi][ni] = (f32x4){0.f, 0.f, 0.f, 0.f};
  const u16* Ab = A + (size_t)bm * 128 * K;
  const u16* Wb = W + (size_t)bn * 128 * K;
  for (int k0 = 0; k0 < K; k0 += 32) {
#pragma unroll
    for (int i = 0; i < 2; ++i) {
      int c = i * 256 + t;
      gload16(Ab + (size_t)(c >> 2) * K + k0 + (c & 3) * 8, &As[c * 8]);
    }
#pragma unroll
    for (int i = 0; i < 2; ++i) {
      int c = i * 256 + t;
      gload16(Wb + (size_t)(c >> 2) * K + k0 + (c & 3) * 8, &Ws[c * 8]);
    }
    __syncthreads();
    bf16x8 af[4], wf[4];
#pragma unroll
    for (int mi = 0; mi < 4; ++mi)
      af[mi] = *(const bf16x8*)&As[(wr + mi * 16 + lr) * 32 + lg * 8];
#pragma unroll
    for (int ni = 0; ni < 4; ++ni)
      wf[ni] = *(const bf16x8*)&Ws[(wc + ni * 16 + lr) * 32 + lg * 8];
#pragma unroll
    for (int mi = 0; mi < 4; ++mi)
#pragma unroll
      for (int ni = 0; ni < 4; ++ni)
        acc[mi][ni] = __builtin_amdgcn_mfma_f32_16x16x32_bf16(af[mi], wf[ni], acc[mi][ni], 0, 0, 0);
    __syncthreads();
  }
#pragma unroll
  for (int mi = 0; mi < 4; ++mi)
#pragma unroll
    for (int ni = 0; ni < 4; ++ni) {
      int col = bn * 128 + wc + ni * 16 + lr;
#pragma unroll
      for (int g = 0; g < 4; ++g) {
        int row = bm * 128 + wr + mi * 16 + lg * 4 + g;
        if (OUTF32)
          Yf[(size_t)row * N + col] = acc[mi][ni][g];
        else
          Yb[(size_t)row * N + col] = f2bf(acc[mi][ni][g]);
      }
    }
}

// ---------------- fused causal attention with TXL rel-shift ----------------
// grid: (16 q-tiles, 64 bh). block: 256 threads = 4 waves, wave w owns q rows
// [i0+16w, i0+16w+16). Per 64-key tile: Sc = qc@K^T, Sp band = qp@relband^T
// (5 col-tiles per wave, LDS-bounced for the diagonal gather), online softmax,
// O += P@V.
__global__ __launch_bounds__(256) void attn_fwd(
    const u16* __restrict__ qcb, const u16* __restrict__ qpb,
    const u16* __restrict__ qkv, const u16* __restrict__ relp,
    u16* __restrict__ out) {
  __shared__ u16 Ks[64][72];        // [key][d] (+8 pad)
  __shared__ u16 Vt[64][72];        // [d][key] transposed (+8 pad)
  __shared__ u16 Rs[128][72];       // rel band rows r0-63 .. r0+64
  __shared__ u16 SpL[4][16][128];   // per-wave Sp band (bf16)
  __shared__ u16 Ps[4][16][72];     // per-wave P tile (bf16)

  const int qt = 15 - (int)blockIdx.x;  // heavy tiles launch first
  const int bh = blockIdx.y;
  const int b = bh >> 4, h = bh & 15;
  const int i0 = qt * 64;
  const int t = threadIdx.x;
  const int w = t >> 6, l = t & 63;
  const int lr = l & 15, lg = l >> 4;

  const u16* Kg = qkv + (size_t)b * S_LEN * 3072 + 1024 + h * 64;
  const u16* Vg = qkv + (size_t)b * S_LEN * 3072 + 2048 + h * 64;
  const u16* Rg = relp + h * 64;

  // q fragments (row-major A-frags): row = lr, k = kc*32 + lg*8 + j
  bf16x8 qcf[2], qpf[2];
  {
    size_t qoff = (size_t)(b * S_LEN + i0 + w * 16 + lr) * 1024 + h * 64;
    qcf[0] = *(const bf16x8*)(qcb + qoff + lg * 8);
    qcf[1] = *(const bf16x8*)(qcb + qoff + 32 + lg * 8);
    qpf[0] = *(const bf16x8*)(qpb + qoff + lg * 8);
    qpf[1] = *(const bf16x8*)(qpb + qoff + 32 + lg * 8);
  }

  float m_run[4], l_run[4];
  f32x4 o_acc[4];
#pragma unroll
  for (int g = 0; g < 4; ++g) { m_run[g] = -1e30f; l_run[g] = 0.f; }
#pragma unroll
  for (int dt = 0; dt < 4; ++dt) o_acc[dt] = (f32x4){0.f, 0.f, 0.f, 0.f};

  for (int j0 = 0; j0 <= i0; j0 += 64) {
    // ---- stage K [64][64] ----
#pragma unroll
    for (int i = 0; i < 2; ++i) {
      int c = i * 256 + t;
      *(u16x8*)&Ks[c >> 3][(c & 7) * 8] =
          *(const u16x8*)(Kg + (size_t)(j0 + (c >> 3)) * 3072 + (c & 7) * 8);
    }
    // ---- stage V transposed -> Vt[d][key] ----
#pragma unroll
    for (int i = 0; i < 2; ++i) {
      int c = i * 256 + t;
      int key = c >> 3, d0 = (c & 7) * 8;
      u16x8 vv = *(const u16x8*)(Vg + (size_t)(j0 + key) * 3072 + d0);
#pragma unroll
      for (int jj = 0; jj < 8; ++jj) Vt[d0 + jj][key] = vv[jj];
    }
    // ---- stage rel band: rows r0-63 .. r0+64 (clamped) ----
    const int r0 = j0 - i0 + (S_LEN - 1);
#pragma unroll
    for (int i = 0; i < 4; ++i) {
      int c = i * 256 + t;
      int brow = c >> 3, seg = c & 7;
      int r = r0 - 63 + brow;
      r = r < 0 ? 0 : (r > S_LEN - 1 ? S_LEN - 1 : r);
      *(u16x8*)&Rs[brow][seg * 8] = *(const u16x8*)(Rg + (size_t)r * 1024 + seg * 8);
    }
    __syncthreads();

    // ---- Sc = qc @ K^T : D[qrow][key] ----
    f32x4 sc[4];
#pragma unroll
    for (int tt = 0; tt < 4; ++tt) {
      sc[tt] = (f32x4){0.f, 0.f, 0.f, 0.f};
#pragma unroll
      for (int kc = 0; kc < 2; ++kc) {
        bf16x8 kf = *(const bf16x8*)&Ks[tt * 16 + lr][kc * 32 + lg * 8];
        sc[tt] = __builtin_amdgcn_mfma_f32_16x16x32_bf16(qcf[kc], kf, sc[tt], 0, 0, 0);
      }
    }
    // ---- Sp band: wave w needs band cols [48-16w, 126-16w] -> tiles 3-w..7-w ----
#pragma unroll
    for (int u5 = 0; u5 < 5; ++u5) {
      int bt = 3 - w + u5;
      f32x4 sp = (f32x4){0.f, 0.f, 0.f, 0.f};
#pragma unroll
      for (int kc = 0; kc < 2; ++kc) {
        bf16x8 rf = *(const bf16x8*)&Rs[bt * 16 + lr][kc * 32 + lg * 8];
        sp = __builtin_amdgcn_mfma_f32_16x16x32_bf16(qpf[kc], rf, sp, 0, 0, 0);
      }
#pragma unroll
      for (int g = 0; g < 4; ++g)
        SpL[w][lg * 4 + g][bt * 16 + lr] = f2bf(sp[g]);
    }

    // ---- gather diag-shifted Sp, mask, scale ----
    float p[4][4];
    float rowmax[4];
#pragma unroll
    for (int g = 0; g < 4; ++g) rowmax[g] = -1e30f;
#pragma unroll
    for (int tt = 0; tt < 4; ++tt) {
#pragma unroll
      for (int g = 0; g < 4; ++g) {
        int ql = lg * 4 + g;
        int iw = w * 16 + ql;
        int jj = tt * 16 + lr;
        float z = (sc[tt][g] + bf2f(SpL[w][ql][jj - iw + 63])) * 0.125f;
        if (j0 + jj > i0 + iw) z = -1e30f;  // causal
        p[tt][g] = z;
        rowmax[g] = fmaxf(rowmax[g], z);
      }
    }
#pragma unroll
    for (int g = 0; g < 4; ++g) {
#pragma unroll
      for (int d = 1; d < 16; d <<= 1)
        rowmax[g] = fmaxf(rowmax[g], __shfl_xor(rowmax[g], d));
    }
    // ---- online softmax update ----
    float corr[4], rs[4];
#pragma unroll
    for (int g = 0; g < 4; ++g) {
      float mnew = fmaxf(m_run[g], rowmax[g]);
      corr[g] = __expf(m_run[g] - mnew);
      m_run[g] = mnew;
      float s = 0.f;
#pragma unroll
      for (int tt = 0; tt < 4; ++tt) {
        float e = __expf(p[tt][g] - mnew);
        p[tt][g] = e;
        s += e;
      }
      rs[g] = s;
    }
#pragma unroll
    for (int g = 0; g < 4; ++g) {
#pragma unroll
      for (int d = 1; d < 16; d <<= 1) rs[g] += __shfl_xor(rs[g], d);
      l_run[g] = l_run[g] * corr[g] + rs[g];
    }
#pragma unroll
    for (int dt = 0; dt < 4; ++dt)
#pragma unroll
      for (int g = 0; g < 4; ++g) o_acc[dt][g] *= corr[g];

    // ---- P -> LDS (layout change D-frag -> A-frag) ----
#pragma unroll
    for (int tt = 0; tt < 4; ++tt)
#pragma unroll
      for (int g = 0; g < 4; ++g)
        Ps[w][lg * 4 + g][tt * 16 + lr] = f2bf(p[tt][g]);
    bf16x8 pf[2];
    pf[0] = *(const bf16x8*)&Ps[w][lr][lg * 8];
    pf[1] = *(const bf16x8*)&Ps[w][lr][32 + lg * 8];
    // ---- O += P @ V ----
#pragma unroll
    for (int dt = 0; dt < 4; ++dt) {
#pragma unroll
      for (int kc = 0; kc < 2; ++kc) {
        bf16x8 vf = *(const bf16x8*)&Vt[dt * 16 + lr][kc * 32 + lg * 8];
        o_acc[dt] = __builtin_amdgcn_mfma_f32_16x16x32_bf16(pf[kc], vf, o_acc[dt], 0, 0, 0);
      }
    }
    __syncthreads();
  }

  // ---- normalize + write [B*S, D] bf16 ----
#pragma unroll
  for (int dt = 0; dt < 4; ++dt) {
    int col = h * 64 + dt * 16 + lr;
#pragma unroll
    for (int g = 0; g < 4; ++g) {
      int row = b * S_LEN + i0 + w * 16 + lg * 4 + g;
      out[(size_t)row * 1024 + col] = f2bf(o_acc[dt][g] / l_run[g]);
    }
  }
}

extern "C" void kernel_launch(void* const* d_in, const int* in_sizes, int n_in,
                              void* d_out, int out_size, void* d_ws, size_t ws_size,
                              hipStream_t stream) {
  const float* x    = (const float*)d_in[0];
  const float* Wqkv = (const float*)d_in[1];
  const float* Wout = (const float*)d_in[2];
  const float* Wpos = (const float*)d_in[3];
  const float* u    = (const float*)d_in[4];
  const float* v    = (const float*)d_in[5];
  const float* rel  = (const float*)d_in[6];
  float* out = (float*)d_out;

  u16* ws      = (u16*)d_ws;
  u16* xb      = ws;                      // 4096x1024
  u16* wqkvb   = xb + 4194304;            // 3072x1024
  u16* woutb   = wqkvb + 3145728;         // 1024x1024
  u16* wposb   = woutb + 1048576;         // 1024x1024
  u16* relb    = wposb + 1048576;         // 1024x1024
  u16* qkvb    = relb + 1048576;          // 4096x3072
  u16* qcb     = qkvb + 12582912;         // 4096x1024
  u16* qpb     = qcb + 4194304;           // 4096x1024
  u16* relproj = qpb + 4194304;           // 1024x1024
  u16* attno   = relproj + 1048576;       // 4096x1024
  // total ws: 73,400,320 bytes

  cvt_bf16<<<4096, 256, 0, stream>>>(x, xb, 4194304);
  cvt_bf16<<<3072, 256, 0, stream>>>(Wqkv, wqkvb, 3145728);
  cvt_bf16<<<1024, 256, 0, stream>>>(Wout, woutb, 1048576);
  cvt_bf16<<<1024, 256, 0, stream>>>(Wpos, wposb, 1048576);
  cvt_bf16<<<1024, 256, 0, stream>>>(rel, relb, 1048576);

  gemm_bt<0><<<dim3(32, 24), 256, 0, stream>>>(xb, wqkvb, nullptr, qkvb, 4096, 3072, 1024);
  gemm_bt<0><<<dim3(8, 8), 256, 0, stream>>>(relb, wposb, nullptr, relproj, 1024, 1024, 1024);
  make_qcqp<<<2048, 256, 0, stream>>>(qkvb, u, v, qcb, qpb);
  attn_fwd<<<dim3(16, 64), 256, 0, stream>>>(qcb, qpb, qkvb, relproj, attno);
  gemm_bt<1><<<dim3(32, 8), 256, 0, stream>>>(attno, woutb, out, nullptr, 4096, 1024, 1024);
}

// Round 3
// 205.786 us; speedup vs baseline: 1.1566x; 1.1566x over previous
//
#include <hip/hip_runtime.h>

#define S_LEN 1024

typedef unsigned short u16;
using bf16x8 = __attribute__((ext_vector_type(8))) short;
using bf16x4 = __attribute__((ext_vector_type(4))) short;
using f32x4  = __attribute__((ext_vector_type(4))) float;
using u16x8  = __attribute__((ext_vector_type(8))) unsigned short;
using u16x4  = __attribute__((ext_vector_type(4))) unsigned short;

__device__ __forceinline__ float bf2f(u16 b) {
  unsigned int u = ((unsigned int)b) << 16;
  return __builtin_bit_cast(float, u);
}
__device__ __forceinline__ u16 f2bf(float f) {
  unsigned int u = __builtin_bit_cast(unsigned int, f);
  unsigned int r = u + 0x7fffu + ((u >> 16) & 1u);
  return (u16)(r >> 16);
}

using gas_p = const __attribute__((address_space(1))) void*;
using las_p = __attribute__((address_space(3))) void*;
__device__ __forceinline__ void gload16(const void* g, void* l) {
  __builtin_amdgcn_global_load_lds((gas_p)g, (las_p)l, 16, 0, 0);
}

// ---------------- merged f32 -> bf16 conversion (5 tensors, 1 launch) ----------------
__global__ __launch_bounds__(256) void cvt_all(const float* __restrict__ x,
    const float* __restrict__ wqkv, const float* __restrict__ wout,
    const float* __restrict__ wpos, const float* __restrict__ rel,
    u16* __restrict__ xb, u16* __restrict__ wqkvb, u16* __restrict__ woutb,
    u16* __restrict__ wposb, u16* __restrict__ relb) {
  int blk = blockIdx.x;
  const float* src; u16* dst; int base;
  if (blk < 4096)      { src = x;    dst = xb;    base = blk; }
  else if (blk < 7168) { src = wqkv; dst = wqkvb; base = blk - 4096; }
  else if (blk < 8192) { src = wout; dst = woutb; base = blk - 7168; }
  else if (blk < 9216) { src = wpos; dst = wposb; base = blk - 8192; }
  else                 { src = rel;  dst = relb;  base = blk - 9216; }
  int i = (base * 256 + threadIdx.x) * 4;
  float4 v = *(const float4*)(src + i);
  u16x4 o;
  o.x = f2bf(v.x); o.y = f2bf(v.y); o.z = f2bf(v.z); o.w = f2bf(v.w);
  *(u16x4*)(dst + i) = o;
}

// ---------------- GEMM: Y = A @ W^T  (A[M,K], W[N,K] bf16 row-major) ----------------
// MODE 0: bf16 out. MODE 1: f32 out. MODE 2: qkv-fused (q cols -> qc=q+u, qp=q+v).
template <int MODE>
__global__ __launch_bounds__(256) void gemm_bt(const u16* __restrict__ A,
    const u16* __restrict__ W, float* __restrict__ Yf, u16* __restrict__ Yb,
    u16* __restrict__ qc, u16* __restrict__ qp,
    const float* __restrict__ uvec, const float* __restrict__ vvec,
    int M, int N, int K) {
  __shared__ __align__(16) u16 As[128 * 32];
  __shared__ __align__(16) u16 Ws[128 * 32];
  const int t = threadIdx.x;
  const int w = t >> 6, l = t & 63;
  const int lr = l & 15, lg = l >> 4;
  const int bm = blockIdx.x, bn = blockIdx.y;
  const int wr = (w >> 1) * 64, wc = (w & 1) * 64;
  f32x4 acc[4][4];
#pragma unroll
  for (int mi = 0; mi < 4; ++mi)
#pragma unroll
    for (int ni = 0; ni < 4; ++ni) acc[mi][ni] = (f32x4){0.f, 0.f, 0.f, 0.f};
  const u16* Ab = A + (size_t)bm * 128 * K;
  const u16* Wb = W + (size_t)bn * 128 * K;
  for (int k0 = 0; k0 < K; k0 += 32) {
#pragma unroll
    for (int i = 0; i < 2; ++i) {
      int c = i * 256 + t;
      gload16(Ab + (size_t)(c >> 2) * K + k0 + (c & 3) * 8, &As[c * 8]);
    }
#pragma unroll
    for (int i = 0; i < 2; ++i) {
      int c = i * 256 + t;
      gload16(Wb + (size_t)(c >> 2) * K + k0 + (c & 3) * 8, &Ws[c * 8]);
    }
    __syncthreads();
    bf16x8 af[4], wf[4];
#pragma unroll
    for (int mi = 0; mi < 4; ++mi)
      af[mi] = *(const bf16x8*)&As[(wr + mi * 16 + lr) * 32 + lg * 8];
#pragma unroll
    for (int ni = 0; ni < 4; ++ni)
      wf[ni] = *(const bf16x8*)&Ws[(wc + ni * 16 + lr) * 32 + lg * 8];
#pragma unroll
    for (int mi = 0; mi < 4; ++mi)
#pragma unroll
      for (int ni = 0; ni < 4; ++ni)
        acc[mi][ni] = __builtin_amdgcn_mfma_f32_16x16x32_bf16(af[mi], wf[ni], acc[mi][ni], 0, 0, 0);
    __syncthreads();
  }
#pragma unroll
  for (int mi = 0; mi < 4; ++mi)
#pragma unroll
    for (int ni = 0; ni < 4; ++ni) {
      int col = bn * 128 + wc + ni * 16 + lr;
      float uu = 0.f, vv = 0.f;
      if (MODE == 2 && col < 1024) { uu = uvec[col]; vv = vvec[col]; }
#pragma unroll
      for (int g = 0; g < 4; ++g) {
        int row = bm * 128 + wr + mi * 16 + lg * 4 + g;
        float val = acc[mi][ni][g];
        if (MODE == 1) {
          Yf[(size_t)row * N + col] = val;
        } else if (MODE == 0) {
          Yb[(size_t)row * N + col] = f2bf(val);
        } else {
          if (col < 1024) {
            qc[(size_t)row * 1024 + col] = f2bf(val + uu);
            qp[(size_t)row * 1024 + col] = f2bf(val + vv);
          } else {
            Yb[(size_t)row * 3072 + col] = f2bf(val);
          }
        }
      }
    }
}

// ---------------- fused causal attention with TXL rel-shift (v2.1) ----------------
// 4 waves/block, wave w owns q rows [i0+16w, i0+16w+16). Fragment-ordered block
// LDS for K/R/V^T (contiguous lane*16B reads), gload_lds staging for K/R,
// shfl-based diagonal gather for the rel band, double-buffered, 1 barrier/iter.
// v2.1 fix: V staging covers all 64 keys (two 256-thread chunks).
__global__ __launch_bounds__(256) void attn_fwd(
    const u16* __restrict__ qcb, const u16* __restrict__ qpb,
    const u16* __restrict__ qkv, const u16* __restrict__ relp,
    u16* __restrict__ out) {
  __shared__ __align__(16) u16 Ksb[2][4096];   // 8 blocks x (64 lanes x 8 elems)
  __shared__ __align__(16) u16 Rsb[2][8192];   // 16 blocks
  __shared__ __align__(16) u16 Vtb[2][4096];   // 8 blocks (V^T)
  __shared__ __align__(16) u16 Ps[4][16][76];  // per-wave P, stride 76

  // XCD-aware bijective swizzle: 1024 wg -> 8 chunks of 128 (8 bh per XCD)
  const int flat = (int)blockIdx.y * 16 + (int)blockIdx.x;
  const int wg = (flat & 7) * 128 + (flat >> 3);
  const int qt = 15 - (wg & 15);  // heavy tiles first within chunk
  const int bh = wg >> 4;
  const int b = bh >> 4, h = bh & 15;
  const int i0 = qt * 64;
  const int nt = qt + 1;
  const int t = threadIdx.x;
  const int w = t >> 6, l = t & 63;
  const int lr = l & 15, lg = l >> 4;

  const u16* Kg = qkv + (size_t)b * S_LEN * 3072 + 1024 + h * 64;
  const u16* Vg = qkv + (size_t)b * S_LEN * 3072 + 2048 + h * 64;
  const u16* Rg = relp + h * 64;

  // q fragments (A-frag: row = lr, k = kc*32 + lg*8 + j)
  bf16x8 qcf[2], qpf[2];
  {
    size_t qoff = (size_t)(b * S_LEN + i0 + w * 16 + lr) * 1024 + h * 64;
    qcf[0] = *(const bf16x8*)(qcb + qoff + lg * 8);
    qcf[1] = *(const bf16x8*)(qcb + qoff + 32 + lg * 8);
    qpf[0] = *(const bf16x8*)(qpb + qoff + lg * 8);
    qpf[1] = *(const bf16x8*)(qpb + qoff + 32 + lg * 8);
  }

  // hoisted gather lanes + conditions (per g): ql = lg*4+g
  int gl4[4]; int cg[4];
#pragma unroll
  for (int g = 0; g < 4; ++g) {
    int ql = lg * 4 + g;
    gl4[g] = (l & 48) | ((lr - ql - 1) & 15);
    cg[g] = (lr > ql) ? 1 : 0;
  }

  // staging helpers
  auto stage_kr = [&](int j0s, int buf) {
    // K: blocks 0..7 = (tt,kc); wave w stages blocks w, w+4
#pragma unroll
    for (int i = 0; i < 2; ++i) {
      int bK = i * 4 + w;
      int ttk = bK >> 1, kc = bK & 1;
      gload16(Kg + (size_t)(j0s + ttk * 16 + lr) * 3072 + kc * 32 + lg * 8,
              &Ksb[buf][(bK * 64 + l) * 8]);
    }
    // R band: blocks 0..15 = (bt,kc); wave w stages w, w+4, w+8, w+12
    const int r0 = j0s - i0 + (S_LEN - 1);
#pragma unroll
    for (int i = 0; i < 4; ++i) {
      int bR = i * 4 + w;
      int btr = bR >> 1, kc = bR & 1;
      int r = r0 - 63 + btr * 16 + lr;
      r = r < 0 ? 0 : (r > S_LEN - 1 ? S_LEN - 1 : r);
      gload16(Rg + (size_t)r * 1024 + kc * 32 + lg * 8,
              &Rsb[buf][(bR * 64 + l) * 8]);
    }
  };
  auto vload = [&](int j0s, u16x8* vv) {
#pragma unroll
    for (int i = 0; i < 2; ++i) {
      int c = i * 256 + t;
      vv[i] = *(const u16x8*)(Vg + (size_t)(j0s + (c >> 3)) * 3072 + (c & 7) * 8);
    }
  };
  auto vstore = [&](int buf, const u16x8* vv) {
#pragma unroll
    for (int i = 0; i < 2; ++i) {
      int c = i * 256 + t;
      int key = c >> 3;
      int d0 = (c & 7) * 8;
#pragma unroll
      for (int j = 0; j < 8; ++j) {
        int d = d0 + j;
        int blk = (d >> 4) * 2 + (key >> 5);
        int lane_s = ((key >> 3) & 3) * 16 + (d & 15);
        Vtb[buf][(blk * 64 + lane_s) * 8 + (key & 7)] = vv[i][j];
      }
    }
  };

  float m_run[4], l_run[4];
  f32x4 o_acc[4];
#pragma unroll
  for (int g = 0; g < 4; ++g) { m_run[g] = -1e30f; l_run[g] = 0.f; }
#pragma unroll
  for (int dt = 0; dt < 4; ++dt) o_acc[dt] = (f32x4){0.f, 0.f, 0.f, 0.f};

  // prologue: stage tile 0 into buf 0
  stage_kr(0, 0);
  {
    u16x8 v0[2];
    vload(0, v0);
    vstore(0, v0);
  }
  __syncthreads();

  for (int kt = 0; kt < nt; ++kt) {
    const int cur = kt & 1, nxt = cur ^ 1;
    const int j0 = kt * 64;
    const int have_nxt = (kt + 1 < nt);
    u16x8 vv[2];
    if (have_nxt) {
      stage_kr(j0 + 64, nxt);
      vload(j0 + 64, vv);
    }

    // ---- Sc = qc @ K^T ----
    f32x4 sc[4];
    __builtin_amdgcn_s_setprio(1);
#pragma unroll
    for (int tt = 0; tt < 4; ++tt) {
      sc[tt] = (f32x4){0.f, 0.f, 0.f, 0.f};
#pragma unroll
      for (int kc = 0; kc < 2; ++kc) {
        bf16x8 kf = *(const bf16x8*)&Ksb[cur][((tt * 2 + kc) * 64 + l) * 8];
        sc[tt] = __builtin_amdgcn_mfma_f32_16x16x32_bf16(qcf[kc], kf, sc[tt], 0, 0, 0);
      }
    }
    // ---- Sp band (5 tiles per wave) ----
    f32x4 sp[5];
#pragma unroll
    for (int u5 = 0; u5 < 5; ++u5) {
      int bt = 3 - w + u5;
      sp[u5] = (f32x4){0.f, 0.f, 0.f, 0.f};
#pragma unroll
      for (int kc = 0; kc < 2; ++kc) {
        bf16x8 rf = *(const bf16x8*)&Rsb[cur][((bt * 2 + kc) * 64 + l) * 8];
        sp[u5] = __builtin_amdgcn_mfma_f32_16x16x32_bf16(qpf[kc], rf, sp[u5], 0, 0, 0);
      }
    }
    __builtin_amdgcn_s_setprio(0);

    // ---- diag gather via shfl (addr is tt-independent), mask, scale ----
    float p[4][4];
    float rowmax[4];
#pragma unroll
    for (int g = 0; g < 4; ++g) rowmax[g] = -1e30f;
#pragma unroll
    for (int g = 0; g < 4; ++g) {
      float bp[5];
#pragma unroll
      for (int u5 = 0; u5 < 5; ++u5) bp[u5] = __shfl(sp[u5][g], gl4[g]);
      int ql = lg * 4 + g;
#pragma unroll
      for (int tt = 0; tt < 4; ++tt) {
        float band = cg[g] ? bp[tt + 1] : bp[tt];
        float z = (sc[tt][g] + band) * 0.125f;
        if (j0 + tt * 16 + lr > i0 + w * 16 + ql) z = -1e30f;  // causal
        p[tt][g] = z;
        rowmax[g] = fmaxf(rowmax[g], z);
      }
    }
#pragma unroll
    for (int g = 0; g < 4; ++g) {
#pragma unroll
      for (int d = 1; d < 16; d <<= 1)
        rowmax[g] = fmaxf(rowmax[g], __shfl_xor(rowmax[g], d));
    }
    // ---- online softmax ----
    float corr[4], rs[4];
#pragma unroll
    for (int g = 0; g < 4; ++g) {
      float mnew = fmaxf(m_run[g], rowmax[g]);
      corr[g] = __expf(m_run[g] - mnew);
      m_run[g] = mnew;
      float s = 0.f;
#pragma unroll
      for (int tt = 0; tt < 4; ++tt) {
        float e = __expf(p[tt][g] - mnew);
        p[tt][g] = e;
        s += e;
      }
      rs[g] = s;
    }
#pragma unroll
    for (int g = 0; g < 4; ++g) {
#pragma unroll
      for (int d = 1; d < 16; d <<= 1) rs[g] += __shfl_xor(rs[g], d);
      l_run[g] = l_run[g] * corr[g] + rs[g];
    }
#pragma unroll
    for (int dt = 0; dt < 4; ++dt)
#pragma unroll
      for (int g = 0; g < 4; ++g) o_acc[dt][g] *= corr[g];

    // ---- P -> LDS (D-frag -> A-frag), stride-76 rows ----
#pragma unroll
    for (int tt = 0; tt < 4; ++tt)
#pragma unroll
      for (int g = 0; g < 4; ++g)
        Ps[w][lg * 4 + g][tt * 16 + lr] = f2bf(p[tt][g]);
    bf16x8 pf[2];
#pragma unroll
    for (int kc = 0; kc < 2; ++kc) {
      bf16x4 plo = *(const bf16x4*)&Ps[w][lr][kc * 32 + lg * 8];
      bf16x4 phi = *(const bf16x4*)&Ps[w][lr][kc * 32 + lg * 8 + 4];
      pf[kc] = __builtin_shufflevector(plo, phi, 0, 1, 2, 3, 4, 5, 6, 7);
    }
    // ---- O += P @ V ----
    __builtin_amdgcn_s_setprio(1);
#pragma unroll
    for (int dt = 0; dt < 4; ++dt) {
#pragma unroll
      for (int kc = 0; kc < 2; ++kc) {
        bf16x8 vf = *(const bf16x8*)&Vtb[cur][((dt * 2 + kc) * 64 + l) * 8];
        o_acc[dt] = __builtin_amdgcn_mfma_f32_16x16x32_bf16(pf[kc], vf, o_acc[dt], 0, 0, 0);
      }
    }
    __builtin_amdgcn_s_setprio(0);
    if (have_nxt) vstore(nxt, vv);
    __syncthreads();
  }

  // ---- normalize + write bf16 [B*S, D] ----
#pragma unroll
  for (int dt = 0; dt < 4; ++dt) {
    int col = h * 64 + dt * 16 + lr;
#pragma unroll
    for (int g = 0; g < 4; ++g) {
      int row = b * S_LEN + i0 + w * 16 + lg * 4 + g;
      out[(size_t)row * 1024 + col] = f2bf(o_acc[dt][g] / l_run[g]);
    }
  }
}

extern "C" void kernel_launch(void* const* d_in, const int* in_sizes, int n_in,
                              void* d_out, int out_size, void* d_ws, size_t ws_size,
                              hipStream_t stream) {
  const float* x    = (const float*)d_in[0];
  const float* Wqkv = (const float*)d_in[1];
  const float* Wout = (const float*)d_in[2];
  const float* Wpos = (const float*)d_in[3];
  const float* u    = (const float*)d_in[4];
  const float* v    = (const float*)d_in[5];
  const float* rel  = (const float*)d_in[6];
  float* out = (float*)d_out;

  u16* ws      = (u16*)d_ws;
  u16* xb      = ws;                      // 4096x1024
  u16* wqkvb   = xb + 4194304;            // 3072x1024
  u16* woutb   = wqkvb + 3145728;         // 1024x1024
  u16* wposb   = woutb + 1048576;         // 1024x1024
  u16* relb    = wposb + 1048576;         // 1024x1024
  u16* qkvb    = relb + 1048576;          // 4096x3072 (k,v parts used)
  u16* qcb     = qkvb + 12582912;         // 4096x1024
  u16* qpb     = qcb + 4194304;           // 4096x1024
  u16* relproj = qpb + 4194304;           // 1024x1024
  u16* attno   = relproj + 1048576;       // 4096x1024

  cvt_all<<<10240, 256, 0, stream>>>(x, Wqkv, Wout, Wpos, rel, xb, wqkvb, woutb, wposb, relb);

  gemm_bt<2><<<dim3(32, 24), 256, 0, stream>>>(xb, wqkvb, nullptr, qkvb, qcb, qpb, u, v, 4096, 3072, 1024);
  gemm_bt<0><<<dim3(8, 8), 256, 0, stream>>>(relb, wposb, nullptr, relproj, nullptr, nullptr, nullptr, nullptr, 1024, 1024, 1024);
  attn_fwd<<<dim3(16, 64), 256, 0, stream>>>(qcb, qpb, qkvb, relproj, attno);
  gemm_bt<1><<<dim3(32, 8), 256, 0, stream>>>(attno, woutb, out, nullptr, nullptr, nullptr, nullptr, nullptr, 4096, 1024, 1024);
}

// Round 4
// 160.103 us; speedup vs baseline: 1.4867x; 1.2853x over previous
//
#include <hip/hip_runtime.h>

#define S_LEN 1024

typedef unsigned short u16;
using bf16x8 = __attribute__((ext_vector_type(8))) short;
using f32x4  = __attribute__((ext_vector_type(4))) float;
using u16x8  = __attribute__((ext_vector_type(8))) unsigned short;
using u16x4  = __attribute__((ext_vector_type(4))) unsigned short;

__device__ __forceinline__ float bf2f(u16 b) {
  unsigned int u = ((unsigned int)b) << 16;
  return __builtin_bit_cast(float, u);
}
__device__ __forceinline__ u16 f2bf(float f) {
  unsigned int u = __builtin_bit_cast(unsigned int, f);
  unsigned int r = u + 0x7fffu + ((u >> 16) & 1u);
  return (u16)(r >> 16);
}

using gas_p = const __attribute__((address_space(1))) void*;
using las_p = __attribute__((address_space(3))) void*;
__device__ __forceinline__ void gload16(const void* g, void* l) {
  __builtin_amdgcn_global_load_lds((gas_p)g, (las_p)l, 16, 0, 0);
}

// ---------------- merged f32 -> bf16 conversion ----------------
__global__ __launch_bounds__(256) void cvt_all(const float* __restrict__ x,
    const float* __restrict__ wqkv, const float* __restrict__ wout,
    const float* __restrict__ wpos, const float* __restrict__ rel,
    u16* __restrict__ xb, u16* __restrict__ wqkvb, u16* __restrict__ woutb,
    u16* __restrict__ wposb, u16* __restrict__ relb) {
  int blk = blockIdx.x;
  const float* src; u16* dst; int base;
  if (blk < 4096)      { src = x;    dst = xb;    base = blk; }
  else if (blk < 7168) { src = wqkv; dst = wqkvb; base = blk - 4096; }
  else if (blk < 8192) { src = wout; dst = woutb; base = blk - 7168; }
  else if (blk < 9216) { src = wpos; dst = wposb; base = blk - 8192; }
  else                 { src = rel;  dst = relb;  base = blk - 9216; }
  int i = (base * 256 + threadIdx.x) * 4;
  float4 v = *(const float4*)(src + i);
  u16x4 o;
  o.x = f2bf(v.x); o.y = f2bf(v.y); o.z = f2bf(v.z); o.w = f2bf(v.w);
  *(u16x4*)(dst + i) = o;
}

// ---------------- GEMM: Y = A @ W^T ----------------
// MODE 0: bf16 out. MODE 1: f32 out. MODE 2: qkv-fused, q cols -> qc=(q+u)/8, qp=(q+v)/8.
// SWZ: 0 none; 1 = grid(32,24) qkv; 2 = grid(32,8) out-proj. BM64: 64-row A tile.
template <int MODE, int SWZ, int BM64>
__global__ __launch_bounds__(256) void gemm_bt(const u16* __restrict__ A,
    const u16* __restrict__ W, float* __restrict__ Yf, u16* __restrict__ Yb,
    u16* __restrict__ qc, u16* __restrict__ qp,
    const float* __restrict__ uvec, const float* __restrict__ vvec,
    int M, int N, int K) {
  constexpr int BM = BM64 ? 64 : 128;
  constexpr int MI = BM64 ? 2 : 4;
  __shared__ __align__(16) u16 As[BM * 32];
  __shared__ __align__(16) u16 Ws[128 * 32];
  const int t = threadIdx.x;
  const int w = t >> 6, l = t & 63;
  const int lr = l & 15, lg = l >> 4;
  int bm, bn;
  if (SWZ == 1) {
    int flat = (int)blockIdx.y * 32 + (int)blockIdx.x;
    int xcd = flat & 7, idx = flat >> 3;
    bm = (xcd & 3) * 8 + (idx & 7);
    bn = (xcd >> 2) * 12 + (idx >> 3);
  } else if (SWZ == 2) {
    int flat = (int)blockIdx.y * 32 + (int)blockIdx.x;
    int xcd = flat & 7, idx = flat >> 3;
    bm = (xcd & 3) * 8 + (idx & 7);
    bn = (xcd >> 2) * 4 + (idx >> 3);
  } else {
    bm = blockIdx.x; bn = blockIdx.y;
  }
  const int wr = BM64 ? ((w >> 1) * 32) : ((w >> 1) * 64);
  const int wc = (w & 1) * 64;
  f32x4 acc[MI][4];
#pragma unroll
  for (int mi = 0; mi < MI; ++mi)
#pragma unroll
    for (int ni = 0; ni < 4; ++ni) acc[mi][ni] = (f32x4){0.f, 0.f, 0.f, 0.f};
  const u16* Ab = A + (size_t)bm * BM * K;
  const u16* Wb = W + (size_t)bn * 128 * K;
  for (int k0 = 0; k0 < K; k0 += 32) {
#pragma unroll
    for (int i = 0; i < (BM64 ? 1 : 2); ++i) {
      int c = i * 256 + t;
      gload16(Ab + (size_t)(c >> 2) * K + k0 + (c & 3) * 8, &As[c * 8]);
    }
#pragma unroll
    for (int i = 0; i < 2; ++i) {
      int c = i * 256 + t;
      gload16(Wb + (size_t)(c >> 2) * K + k0 + (c & 3) * 8, &Ws[c * 8]);
    }
    __syncthreads();
    bf16x8 af[MI], wf[4];
#pragma unroll
    for (int mi = 0; mi < MI; ++mi)
      af[mi] = *(const bf16x8*)&As[(wr + mi * 16 + lr) * 32 + lg * 8];
#pragma unroll
    for (int ni = 0; ni < 4; ++ni)
      wf[ni] = *(const bf16x8*)&Ws[(wc + ni * 16 + lr) * 32 + lg * 8];
    __builtin_amdgcn_s_setprio(1);
#pragma unroll
    for (int mi = 0; mi < MI; ++mi)
#pragma unroll
      for (int ni = 0; ni < 4; ++ni)
        acc[mi][ni] = __builtin_amdgcn_mfma_f32_16x16x32_bf16(af[mi], wf[ni], acc[mi][ni], 0, 0, 0);
    __builtin_amdgcn_s_setprio(0);
    __syncthreads();
  }
#pragma unroll
  for (int mi = 0; mi < MI; ++mi)
#pragma unroll
    for (int ni = 0; ni < 4; ++ni) {
      int col = bn * 128 + wc + ni * 16 + lr;
      float uu = 0.f, vv = 0.f;
      if (MODE == 2 && col < 1024) { uu = uvec[col]; vv = vvec[col]; }
#pragma unroll
      for (int g = 0; g < 4; ++g) {
        int row = bm * BM + wr + mi * 16 + lg * 4 + g;
        float val = acc[mi][ni][g];
        if (MODE == 1) {
          Yf[(size_t)row * N + col] = val;
        } else if (MODE == 0) {
          Yb[(size_t)row * N + col] = f2bf(val);
        } else {
          if (col < 1024) {
            qc[(size_t)row * 1024 + col] = f2bf((val + uu) * 0.125f);
            qp[(size_t)row * 1024 + col] = f2bf((val + vv) * 0.125f);
          } else {
            Yb[(size_t)row * 3072 + col] = f2bf(val);
          }
        }
      }
    }
}

// ---------------- fused causal attention with TXL rel-shift (v3) ----------------
// Block = (bh, qt-pair {15-sub, sub}) -> 17 k-tiles/block, perfectly balanced.
// f32 score roundtrip through LDS: D-frag writes, A-frag reads; reductions on the
// A-frag side (15 in-reg ops + 2 shfl_xor). R band via 3-slot sliding chunks.
__global__ __launch_bounds__(256) void attn_fwd(
    const u16* __restrict__ qcb, const u16* __restrict__ qpb,
    const u16* __restrict__ qkv, const u16* __restrict__ relp,
    u16* __restrict__ out) {
  __shared__ __align__(16) u16 Ksb[2][4096];     // 8 frag-blocks x 64 lanes x 8
  __shared__ __align__(16) u16 Vtb[2][4096];     // V^T, 8 frag-blocks
  __shared__ __align__(16) u16 Rs3[3][4096];     // 3 sliding 64-row chunks
  __shared__ __align__(16) float Psf[4][16][68]; // per-wave f32 scores [q][k]

  const int flat = (int)blockIdx.y * 8 + (int)blockIdx.x;
  const int wg = (flat & 7) * 64 + (flat >> 3);  // XCD-contiguous chunks of 64
  const int sub = wg & 7;
  const int bh = wg >> 3;
  const int b = bh >> 4, h = bh & 15;
  const int t = threadIdx.x;
  const int w = t >> 6, l = t & 63;
  const int lr = l & 15, lg = l >> 4;

  const u16* Kg = qkv + (size_t)b * S_LEN * 3072 + 1024 + h * 64;
  const u16* Vg = qkv + (size_t)b * S_LEN * 3072 + 2048 + h * 64;
  const u16* Rg = relp + h * 64;

  // hoisted band-gather lanes + conditions (per g): ql = lg*4+g
  int gl4[4], cg[4];
#pragma unroll
  for (int g = 0; g < 4; ++g) {
    int ql = lg * 4 + g;
    gl4[g] = (l & 48) | ((lr - ql - 1) & 15);
    cg[g] = (lr > ql) ? 1 : 0;
  }

  for (int half = 0; half < 2; ++half) {
    const int qt = half ? sub : (15 - sub);
    const int i0 = qt * 64;
    const int nt = qt + 1;

    // q fragments (A-frag: row = lr, k = kc*32 + lg*8 + j); pre-scaled by 1/8
    bf16x8 qcf[2], qpf[2];
    {
      size_t qoff = (size_t)(b * S_LEN + i0 + w * 16 + lr) * 1024 + h * 64;
      qcf[0] = *(const bf16x8*)(qcb + qoff + lg * 8);
      qcf[1] = *(const bf16x8*)(qcb + qoff + 32 + lg * 8);
      qpf[0] = *(const bf16x8*)(qpb + qoff + lg * 8);
      qpf[1] = *(const bf16x8*)(qpb + qoff + 32 + lg * 8);
    }

    auto stage_k = [&](int j0s, int buf) {
#pragma unroll
      for (int i = 0; i < 2; ++i) {
        int bK = i * 4 + w;
        int ttk = bK >> 1, kc = bK & 1;
        gload16(Kg + (size_t)(j0s + ttk * 16 + lr) * 3072 + kc * 32 + lg * 8,
                &Ksb[buf][bK * 512 + l * 8]);
      }
    };
    // chunk Gloc (local, 0-based): global chunk G = 15-qt+Gloc, rows G*64..+63
    auto stage_rchunk = [&](int Gloc, int slot) {
      int Gg = 15 - qt + Gloc;
#pragma unroll
      for (int i = 0; i < 2; ++i) {
        int bR = i * 4 + w;
        int btc = bR >> 1, kc = bR & 1;
        int r = Gg * 64 + btc * 16 + lr;
        r = r > S_LEN - 1 ? S_LEN - 1 : r;
        gload16(Rg + (size_t)r * 1024 + kc * 32 + lg * 8,
                &Rs3[slot][bR * 512 + l * 8]);
      }
    };
    auto vload = [&](int j0s, u16x8* vv) {
#pragma unroll
      for (int i = 0; i < 2; ++i) {
        int c = i * 256 + t;
        vv[i] = *(const u16x8*)(Vg + (size_t)(j0s + (c >> 3)) * 3072 + (c & 7) * 8);
      }
    };
    auto vstore = [&](int buf, const u16x8* vv) {
#pragma unroll
      for (int i = 0; i < 2; ++i) {
        int c = i * 256 + t;
        int key = c >> 3;
        int d0 = (c & 7) * 8;
#pragma unroll
        for (int j = 0; j < 8; ++j) {
          int d = d0 + j;
          int blk = (d >> 4) * 2 + (key >> 5);
          int lane_s = ((key >> 3) & 3) * 16 + (d & 15);
          Vtb[buf][(blk * 64 + lane_s) * 8 + (key & 7)] = vv[i][j];
        }
      }
    };

    float m_run = -1e30f, l_run = 0.f;
    f32x4 o_acc[4];
#pragma unroll
    for (int dt = 0; dt < 4; ++dt) o_acc[dt] = (f32x4){0.f, 0.f, 0.f, 0.f};

    // prologue: K/V tile 0, R chunks 0,1
    stage_k(0, 0);
    stage_rchunk(0, 0);
    stage_rchunk(1, 1);
    {
      u16x8 v0[2];
      vload(0, v0);
      vstore(0, v0);
    }
    __syncthreads();

    int sA = 0, sB = 1, sC = 2;
    for (int kt = 0; kt < nt; ++kt) {
      const int cur = kt & 1, nxt = cur ^ 1;
      const int j0 = kt * 64;
      const int have_nxt = (kt + 1 < nt);
      u16x8 vv[2];
      if (have_nxt) {
        stage_k(j0 + 64, nxt);
        stage_rchunk(kt + 2, sC);
        vload(j0 + 64, vv);
      }

      // ---- Sc = qc @ K^T (D-frag: q = lg*4+g, k = tt*16+lr) ----
      f32x4 sc[4];
      __builtin_amdgcn_s_setprio(1);
#pragma unroll
      for (int tt = 0; tt < 4; ++tt) {
        sc[tt] = (f32x4){0.f, 0.f, 0.f, 0.f};
#pragma unroll
        for (int kc = 0; kc < 2; ++kc) {
          bf16x8 kf = *(const bf16x8*)&Ksb[cur][(tt * 2 + kc) * 512 + l * 8];
          sc[tt] = __builtin_amdgcn_mfma_f32_16x16x32_bf16(qcf[kc], kf, sc[tt], 0, 0, 0);
        }
      }
      // ---- Sp band (5 tiles per wave), window = chunks {sA, sB} ----
      f32x4 sp[5];
#pragma unroll
      for (int u5 = 0; u5 < 5; ++u5) {
        int bt = 3 - w + u5;
        const u16* rb = (bt & 4) ? &Rs3[sB][0] : &Rs3[sA][0];
        int btc = bt & 3;
        sp[u5] = (f32x4){0.f, 0.f, 0.f, 0.f};
#pragma unroll
        for (int kc = 0; kc < 2; ++kc) {
          bf16x8 rf = *(const bf16x8*)&rb[(btc * 2 + kc) * 512 + l * 8];
          sp[u5] = __builtin_amdgcn_mfma_f32_16x16x32_bf16(qpf[kc], rf, sp[u5], 0, 0, 0);
        }
      }
      __builtin_amdgcn_s_setprio(0);

      // ---- band gather (shfl), add, causal mask, write f32 scores to LDS ----
#pragma unroll
      for (int g = 0; g < 4; ++g) {
        float bp[5];
#pragma unroll
        for (int u5 = 0; u5 < 5; ++u5) bp[u5] = __shfl(sp[u5][g], gl4[g]);
        int ql = lg * 4 + g;
#pragma unroll
        for (int tt = 0; tt < 4; ++tt) {
          float band = cg[g] ? bp[tt + 1] : bp[tt];
          float z = sc[tt][g] + band;  // scale folded into qc/qp
          if (j0 + tt * 16 + lr > i0 + w * 16 + ql) z = -1e30f;
          Psf[w][ql][tt * 16 + lr] = z;
        }
      }

      // ---- A-frag-side softmax: lane(lr,lg) holds q=lr, k = kc*32+lg*8+j ----
      float zz[2][8];
#pragma unroll
      for (int kc = 0; kc < 2; ++kc)
#pragma unroll
        for (int h4 = 0; h4 < 2; ++h4) {
          float4 rr = *(const float4*)&Psf[w][lr][kc * 32 + lg * 8 + h4 * 4];
          zz[kc][h4 * 4 + 0] = rr.x; zz[kc][h4 * 4 + 1] = rr.y;
          zz[kc][h4 * 4 + 2] = rr.z; zz[kc][h4 * 4 + 3] = rr.w;
        }
      float mt = zz[0][0];
#pragma unroll
      for (int kc = 0; kc < 2; ++kc)
#pragma unroll
        for (int j = 0; j < 8; ++j) mt = fmaxf(mt, zz[kc][j]);
      mt = fmaxf(mt, __shfl_xor(mt, 16));
      mt = fmaxf(mt, __shfl_xor(mt, 32));
      float mnew = fmaxf(m_run, mt);
      float corr = __expf(m_run - mnew);
      m_run = mnew;
      float s = 0.f;
#pragma unroll
      for (int kc = 0; kc < 2; ++kc)
#pragma unroll
        for (int j = 0; j < 8; ++j) {
          float e = __expf(zz[kc][j] - mnew);
          zz[kc][j] = e;
          s += e;
        }
      s += __shfl_xor(s, 16);
      s += __shfl_xor(s, 32);
      l_run = l_run * corr + s;

      // ---- rescale O (corr per o-row via bpermute from lane q') ----
      float co[4];
#pragma unroll
      for (int g = 0; g < 4; ++g) co[g] = __shfl(corr, lg * 4 + g);
#pragma unroll
      for (int dt = 0; dt < 4; ++dt)
#pragma unroll
        for (int g = 0; g < 4; ++g) o_acc[dt][g] *= co[g];

      // ---- pack P to bf16 A-frags (already in A layout) ----
      bf16x8 pf[2];
#pragma unroll
      for (int kc = 0; kc < 2; ++kc)
#pragma unroll
        for (int j = 0; j < 8; ++j) pf[kc][j] = (short)f2bf(zz[kc][j]);

      // ---- O += P @ V ----
      __builtin_amdgcn_s_setprio(1);
#pragma unroll
      for (int dt = 0; dt < 4; ++dt) {
#pragma unroll
        for (int kc = 0; kc < 2; ++kc) {
          bf16x8 vf = *(const bf16x8*)&Vtb[cur][(dt * 2 + kc) * 512 + l * 8];
          o_acc[dt] = __builtin_amdgcn_mfma_f32_16x16x32_bf16(pf[kc], vf, o_acc[dt], 0, 0, 0);
        }
      }
      __builtin_amdgcn_s_setprio(0);
      if (have_nxt) vstore(nxt, vv);
      __syncthreads();
      int stmp = sA; sA = sB; sB = sC; sC = stmp;
    }

    // ---- normalize (l via bpermute) + write bf16 [B*S, D] ----
    float ll[4];
#pragma unroll
    for (int g = 0; g < 4; ++g) ll[g] = __shfl(l_run, lg * 4 + g);
#pragma unroll
    for (int dt = 0; dt < 4; ++dt) {
      int col = h * 64 + dt * 16 + lr;
#pragma unroll
      for (int g = 0; g < 4; ++g) {
        int row = b * S_LEN + i0 + w * 16 + lg * 4 + g;
        out[(size_t)row * 1024 + col] = f2bf(o_acc[dt][g] / ll[g]);
      }
    }
  }
}

extern "C" void kernel_launch(void* const* d_in, const int* in_sizes, int n_in,
                              void* d_out, int out_size, void* d_ws, size_t ws_size,
                              hipStream_t stream) {
  const float* x    = (const float*)d_in[0];
  const float* Wqkv = (const float*)d_in[1];
  const float* Wout = (const float*)d_in[2];
  const float* Wpos = (const float*)d_in[3];
  const float* u    = (const float*)d_in[4];
  const float* v    = (const float*)d_in[5];
  const float* rel  = (const float*)d_in[6];
  float* out = (float*)d_out;

  u16* ws      = (u16*)d_ws;
  u16* xb      = ws;                      // 4096x1024
  u16* wqkvb   = xb + 4194304;            // 3072x1024
  u16* woutb   = wqkvb + 3145728;         // 1024x1024
  u16* wposb   = woutb + 1048576;         // 1024x1024
  u16* relb    = wposb + 1048576;         // 1024x1024
  u16* qkvb    = relb + 1048576;          // 4096x3072 (k,v parts used)
  u16* qcb     = qkvb + 12582912;         // 4096x1024
  u16* qpb     = qcb + 4194304;           // 4096x1024
  u16* relproj = qpb + 4194304;           // 1024x1024
  u16* attno   = relproj + 1048576;       // 4096x1024

  cvt_all<<<10240, 256, 0, stream>>>(x, Wqkv, Wout, Wpos, rel, xb, wqkvb, woutb, wposb, relb);

  gemm_bt<2, 1, 0><<<dim3(32, 24), 256, 0, stream>>>(xb, wqkvb, nullptr, qkvb, qcb, qpb, u, v, 4096, 3072, 1024);
  gemm_bt<0, 0, 1><<<dim3(16, 8), 256, 0, stream>>>(relb, wposb, nullptr, relproj, nullptr, nullptr, nullptr, nullptr, 1024, 1024, 1024);
  attn_fwd<<<dim3(8, 64), 256, 0, stream>>>(qcb, qpb, qkvb, relproj, attno);
  gemm_bt<1, 2, 0><<<dim3(32, 8), 256, 0, stream>>>(attno, woutb, out, nullptr, nullptr, nullptr, nullptr, nullptr, 4096, 1024, 1024);
}

// Round 6
// 151.063 us; speedup vs baseline: 1.5757x; 1.0598x over previous
//
#include <hip/hip_runtime.h>

#define S_LEN 1024

typedef unsigned short u16;
using bf16x8 = __attribute__((ext_vector_type(8))) short;
using bf16x4 = __attribute__((ext_vector_type(4))) short;
using f32x4  = __attribute__((ext_vector_type(4))) float;
using u16x8  = __attribute__((ext_vector_type(8))) unsigned short;
using u16x4  = __attribute__((ext_vector_type(4))) unsigned short;

__device__ __forceinline__ float bf2f(u16 b) {
  unsigned int u = ((unsigned int)b) << 16;
  return __builtin_bit_cast(float, u);
}
__device__ __forceinline__ u16 f2bf(float f) {
  unsigned int u = __builtin_bit_cast(unsigned int, f);
  unsigned int r = u + 0x7fffu + ((u >> 16) & 1u);
  return (u16)(r >> 16);
}

using gas_p = const __attribute__((address_space(1))) void*;
using las_p = __attribute__((address_space(3))) void*;
__device__ __forceinline__ void gload16(const void* g, void* l) {
  __builtin_amdgcn_global_load_lds((gas_p)g, (las_p)l, 16, 0, 0);
}

// ---------------- merged f32 -> bf16 conversion ----------------
__global__ __launch_bounds__(256) void cvt_all(const float* __restrict__ x,
    const float* __restrict__ wqkv, const float* __restrict__ wout,
    const float* __restrict__ wpos, const float* __restrict__ rel,
    u16* __restrict__ xb, u16* __restrict__ wqkvb, u16* __restrict__ woutb,
    u16* __restrict__ wposb, u16* __restrict__ relb) {
  int blk = blockIdx.x;
  const float* src; u16* dst; int base;
  if (blk < 4096)      { src = x;    dst = xb;    base = blk; }
  else if (blk < 7168) { src = wqkv; dst = wqkvb; base = blk - 4096; }
  else if (blk < 8192) { src = wout; dst = woutb; base = blk - 7168; }
  else if (blk < 9216) { src = wpos; dst = wposb; base = blk - 8192; }
  else                 { src = rel;  dst = relb;  base = blk - 9216; }
  int i = (base * 256 + threadIdx.x) * 4;
  float4 v = *(const float4*)(src + i);
  u16x4 o;
  o.x = f2bf(v.x); o.y = f2bf(v.y); o.z = f2bf(v.z); o.w = f2bf(v.w);
  *(u16x4*)(dst + i) = o;
}

// ---------------- GEMM: Y = A @ W^T (double-buffered, stage-ahead) ----------------
// MODE 0: bf16 out. MODE 1: f32 out. MODE 2: qkv-fused, q cols -> qc=(q+u)/8, qp=(q+v)/8.
// SWZ: 1 = XCD swizzle for grid(32,24). BM64: 64-row A tile.
template <int MODE, int SWZ, int BM64>
__global__ __launch_bounds__(256) void gemm_bt(const u16* __restrict__ A,
    const u16* __restrict__ W, float* __restrict__ Yf, u16* __restrict__ Yb,
    u16* __restrict__ qc, u16* __restrict__ qp,
    const float* __restrict__ uvec, const float* __restrict__ vvec,
    int M, int N, int K) {
  constexpr int BM = BM64 ? 64 : 128;
  constexpr int MI = BM64 ? 2 : 4;
  __shared__ __align__(16) u16 As[2][BM * 32];
  __shared__ __align__(16) u16 Ws[2][128 * 32];
  const int t = threadIdx.x;
  const int w = t >> 6, l = t & 63;
  const int lr = l & 15, lg = l >> 4;
  int bm, bn;
  if (SWZ == 1) {
    int flat = (int)blockIdx.y * 32 + (int)blockIdx.x;
    int xcd = flat & 7, idx = flat >> 3;
    bm = (xcd & 3) * 8 + (idx & 7);
    bn = (xcd >> 2) * 12 + (idx >> 3);
  } else {
    bm = blockIdx.x; bn = blockIdx.y;
  }
  const int wr = BM64 ? ((w >> 1) * 32) : ((w >> 1) * 64);
  const int wc = (w & 1) * 64;
  f32x4 acc[MI][4];
#pragma unroll
  for (int mi = 0; mi < MI; ++mi)
#pragma unroll
    for (int ni = 0; ni < 4; ++ni) acc[mi][ni] = (f32x4){0.f, 0.f, 0.f, 0.f};
  const u16* Ab = A + (size_t)bm * BM * K;
  const u16* Wb = W + (size_t)bn * 128 * K;

  auto stage = [&](int k0, int buf) {
#pragma unroll
    for (int i = 0; i < (BM64 ? 1 : 2); ++i) {
      int c = i * 256 + t;
      gload16(Ab + (size_t)(c >> 2) * K + k0 + (c & 3) * 8, &As[buf][c * 8]);
    }
#pragma unroll
    for (int i = 0; i < 2; ++i) {
      int c = i * 256 + t;
      gload16(Wb + (size_t)(c >> 2) * K + k0 + (c & 3) * 8, &Ws[buf][c * 8]);
    }
  };

  stage(0, 0);
  __syncthreads();
  for (int k0 = 0; k0 < K; k0 += 32) {
    const int cur = (k0 >> 5) & 1;
    if (k0 + 32 < K) stage(k0 + 32, cur ^ 1);  // overlaps compute below
    bf16x8 af[MI], wf[4];
#pragma unroll
    for (int mi = 0; mi < MI; ++mi)
      af[mi] = *(const bf16x8*)&As[cur][(wr + mi * 16 + lr) * 32 + lg * 8];
#pragma unroll
    for (int ni = 0; ni < 4; ++ni)
      wf[ni] = *(const bf16x8*)&Ws[cur][(wc + ni * 16 + lr) * 32 + lg * 8];
    __builtin_amdgcn_s_setprio(1);
#pragma unroll
    for (int mi = 0; mi < MI; ++mi)
#pragma unroll
      for (int ni = 0; ni < 4; ++ni)
        acc[mi][ni] = __builtin_amdgcn_mfma_f32_16x16x32_bf16(af[mi], wf[ni], acc[mi][ni], 0, 0, 0);
    __builtin_amdgcn_s_setprio(0);
    __syncthreads();
  }
#pragma unroll
  for (int mi = 0; mi < MI; ++mi)
#pragma unroll
    for (int ni = 0; ni < 4; ++ni) {
      int col = bn * 128 + wc + ni * 16 + lr;
      float uu = 0.f, vv = 0.f;
      if (MODE == 2 && col < 1024) { uu = uvec[col]; vv = vvec[col]; }
#pragma unroll
      for (int g = 0; g < 4; ++g) {
        int row = bm * BM + wr + mi * 16 + lg * 4 + g;
        float val = acc[mi][ni][g];
        if (MODE == 1) {
          Yf[(size_t)row * N + col] = val;
        } else if (MODE == 0) {
          Yb[(size_t)row * N + col] = f2bf(val);
        } else {
          if (col < 1024) {
            qc[(size_t)row * 1024 + col] = f2bf((val + uu) * 0.125f);
            qp[(size_t)row * 1024 + col] = f2bf((val + vv) * 0.125f);
          } else {
            Yb[(size_t)row * 3072 + col] = f2bf(val);
          }
        }
      }
    }
}

// ---------------- fused causal attention with TXL rel-shift (v3, proven) ----------------
// Balanced qt-pairs {15-sub, sub} (17 k-tiles/block), f32 score LDS roundtrip,
// A-frag-side softmax, 3-slot sliding R band, frag-block K/V^T LDS.
__global__ __launch_bounds__(256) void attn_fwd(
    const u16* __restrict__ qcb, const u16* __restrict__ qpb,
    const u16* __restrict__ qkv, const u16* __restrict__ relp,
    u16* __restrict__ out) {
  __shared__ __align__(16) u16 Ksb[2][4096];     // 8 frag-blocks x 64 lanes x 8
  __shared__ __align__(16) u16 Vtb[2][4096];     // V^T, 8 frag-blocks
  __shared__ __align__(16) u16 Rs3[3][4096];     // 3 sliding 64-row chunks
  __shared__ __align__(16) float Psf[4][16][68]; // per-wave f32 scores [q][k]

  const int flat = (int)blockIdx.y * 8 + (int)blockIdx.x;
  const int wg = (flat & 7) * 64 + (flat >> 3);  // XCD-contiguous chunks of 64
  const int sub = wg & 7;
  const int bh = wg >> 3;
  const int b = bh >> 4, h = bh & 15;
  const int t = threadIdx.x;
  const int w = t >> 6, l = t & 63;
  const int lr = l & 15, lg = l >> 4;

  const u16* Kg = qkv + (size_t)b * S_LEN * 3072 + 1024 + h * 64;
  const u16* Vg = qkv + (size_t)b * S_LEN * 3072 + 2048 + h * 64;
  const u16* Rg = relp + h * 64;

  int gl4[4], cg[4];
#pragma unroll
  for (int g = 0; g < 4; ++g) {
    int ql = lg * 4 + g;
    gl4[g] = (l & 48) | ((lr - ql - 1) & 15);
    cg[g] = (lr > ql) ? 1 : 0;
  }

  for (int half = 0; half < 2; ++half) {
    const int qt = half ? sub : (15 - sub);
    const int i0 = qt * 64;
    const int nt = qt + 1;

    bf16x8 qcf[2], qpf[2];
    {
      size_t qoff = (size_t)(b * S_LEN + i0 + w * 16 + lr) * 1024 + h * 64;
      qcf[0] = *(const bf16x8*)(qcb + qoff + lg * 8);
      qcf[1] = *(const bf16x8*)(qcb + qoff + 32 + lg * 8);
      qpf[0] = *(const bf16x8*)(qpb + qoff + lg * 8);
      qpf[1] = *(const bf16x8*)(qpb + qoff + 32 + lg * 8);
    }

    auto stage_k = [&](int j0s, int buf) {
#pragma unroll
      for (int i = 0; i < 2; ++i) {
        int bK = i * 4 + w;
        int ttk = bK >> 1, kc = bK & 1;
        gload16(Kg + (size_t)(j0s + ttk * 16 + lr) * 3072 + kc * 32 + lg * 8,
                &Ksb[buf][bK * 512 + l * 8]);
      }
    };
    auto stage_rchunk = [&](int Gloc, int slot) {
      int Gg = 15 - qt + Gloc;
#pragma unroll
      for (int i = 0; i < 2; ++i) {
        int bR = i * 4 + w;
        int btc = bR >> 1, kc = bR & 1;
        int r = Gg * 64 + btc * 16 + lr;
        r = r > S_LEN - 1 ? S_LEN - 1 : r;
        gload16(Rg + (size_t)r * 1024 + kc * 32 + lg * 8,
                &Rs3[slot][bR * 512 + l * 8]);
      }
    };
    auto vload = [&](int j0s, u16x8* vv) {
#pragma unroll
      for (int i = 0; i < 2; ++i) {
        int c = i * 256 + t;
        vv[i] = *(const u16x8*)(Vg + (size_t)(j0s + (c >> 3)) * 3072 + (c & 7) * 8);
      }
    };
    auto vstore = [&](int buf, const u16x8* vv) {
#pragma unroll
      for (int i = 0; i < 2; ++i) {
        int c = i * 256 + t;
        int key = c >> 3;
        int d0 = (c & 7) * 8;
#pragma unroll
        for (int j = 0; j < 8; ++j) {
          int d = d0 + j;
          int blk = (d >> 4) * 2 + (key >> 5);
          int lane_s = ((key >> 3) & 3) * 16 + (d & 15);
          Vtb[buf][(blk * 64 + lane_s) * 8 + (key & 7)] = vv[i][j];
        }
      }
    };

    float m_run = -1e30f, l_run = 0.f;
    f32x4 o_acc[4];
#pragma unroll
    for (int dt = 0; dt < 4; ++dt) o_acc[dt] = (f32x4){0.f, 0.f, 0.f, 0.f};

    stage_k(0, 0);
    stage_rchunk(0, 0);
    stage_rchunk(1, 1);
    {
      u16x8 v0[2];
      vload(0, v0);
      vstore(0, v0);
    }
    __syncthreads();

    int sA = 0, sB = 1, sC = 2;
    for (int kt = 0; kt < nt; ++kt) {
      const int cur = kt & 1, nxt = cur ^ 1;
      const int j0 = kt * 64;
      const int have_nxt = (kt + 1 < nt);
      u16x8 vv[2];
      if (have_nxt) {
        stage_k(j0 + 64, nxt);
        stage_rchunk(kt + 2, sC);
        vload(j0 + 64, vv);
      }

      // ---- Sc = qc @ K^T ----
      f32x4 sc[4];
      __builtin_amdgcn_s_setprio(1);
#pragma unroll
      for (int tt = 0; tt < 4; ++tt) {
        sc[tt] = (f32x4){0.f, 0.f, 0.f, 0.f};
#pragma unroll
        for (int kc = 0; kc < 2; ++kc) {
          bf16x8 kf = *(const bf16x8*)&Ksb[cur][(tt * 2 + kc) * 512 + l * 8];
          sc[tt] = __builtin_amdgcn_mfma_f32_16x16x32_bf16(qcf[kc], kf, sc[tt], 0, 0, 0);
        }
      }
      // ---- Sp band (5 tiles per wave) ----
      f32x4 sp[5];
#pragma unroll
      for (int u5 = 0; u5 < 5; ++u5) {
        int bt = 3 - w + u5;
        const u16* rb = (bt & 4) ? &Rs3[sB][0] : &Rs3[sA][0];
        int btc = bt & 3;
        sp[u5] = (f32x4){0.f, 0.f, 0.f, 0.f};
#pragma unroll
        for (int kc = 0; kc < 2; ++kc) {
          bf16x8 rf = *(const bf16x8*)&rb[(btc * 2 + kc) * 512 + l * 8];
          sp[u5] = __builtin_amdgcn_mfma_f32_16x16x32_bf16(qpf[kc], rf, sp[u5], 0, 0, 0);
        }
      }
      __builtin_amdgcn_s_setprio(0);

      // ---- band gather (shfl), add, causal mask, f32 scores -> LDS ----
#pragma unroll
      for (int g = 0; g < 4; ++g) {
        float bp[5];
#pragma unroll
        for (int u5 = 0; u5 < 5; ++u5) bp[u5] = __shfl(sp[u5][g], gl4[g]);
        int ql = lg * 4 + g;
#pragma unroll
        for (int tt = 0; tt < 4; ++tt) {
          float band = cg[g] ? bp[tt + 1] : bp[tt];
          float z = sc[tt][g] + band;
          if (j0 + tt * 16 + lr > i0 + w * 16 + ql) z = -1e30f;
          Psf[w][ql][tt * 16 + lr] = z;
        }
      }

      // ---- A-frag-side softmax ----
      float zz[2][8];
#pragma unroll
      for (int kc = 0; kc < 2; ++kc)
#pragma unroll
        for (int h4 = 0; h4 < 2; ++h4) {
          float4 rr = *(const float4*)&Psf[w][lr][kc * 32 + lg * 8 + h4 * 4];
          zz[kc][h4 * 4 + 0] = rr.x; zz[kc][h4 * 4 + 1] = rr.y;
          zz[kc][h4 * 4 + 2] = rr.z; zz[kc][h4 * 4 + 3] = rr.w;
        }
      float mt = zz[0][0];
#pragma unroll
      for (int kc = 0; kc < 2; ++kc)
#pragma unroll
        for (int j = 0; j < 8; ++j) mt = fmaxf(mt, zz[kc][j]);
      mt = fmaxf(mt, __shfl_xor(mt, 16));
      mt = fmaxf(mt, __shfl_xor(mt, 32));
      float mnew = fmaxf(m_run, mt);
      float corr = __expf(m_run - mnew);
      m_run = mnew;
      float s = 0.f;
#pragma unroll
      for (int kc = 0; kc < 2; ++kc)
#pragma unroll
        for (int j = 0; j < 8; ++j) {
          float e = __expf(zz[kc][j] - mnew);
          zz[kc][j] = e;
          s += e;
        }
      s += __shfl_xor(s, 16);
      s += __shfl_xor(s, 32);
      l_run = l_run * corr + s;

      float co[4];
#pragma unroll
      for (int g = 0; g < 4; ++g) co[g] = __shfl(corr, lg * 4 + g);
#pragma unroll
      for (int dt = 0; dt < 4; ++dt)
#pragma unroll
        for (int g = 0; g < 4; ++g) o_acc[dt][g] *= co[g];

      bf16x8 pf[2];
#pragma unroll
      for (int kc = 0; kc < 2; ++kc)
#pragma unroll
        for (int j = 0; j < 8; ++j) pf[kc][j] = (short)f2bf(zz[kc][j]);

      // ---- O += P @ V ----
      __builtin_amdgcn_s_setprio(1);
#pragma unroll
      for (int dt = 0; dt < 4; ++dt) {
#pragma unroll
        for (int kc = 0; kc < 2; ++kc) {
          bf16x8 vf = *(const bf16x8*)&Vtb[cur][(dt * 2 + kc) * 512 + l * 8];
          o_acc[dt] = __builtin_amdgcn_mfma_f32_16x16x32_bf16(pf[kc], vf, o_acc[dt], 0, 0, 0);
        }
      }
      __builtin_amdgcn_s_setprio(0);
      if (have_nxt) vstore(nxt, vv);
      __syncthreads();
      int stmp = sA; sA = sB; sB = sC; sC = stmp;
    }

    float ll[4];
#pragma unroll
    for (int g = 0; g < 4; ++g) ll[g] = __shfl(l_run, lg * 4 + g);
#pragma unroll
    for (int dt = 0; dt < 4; ++dt) {
      int col = h * 64 + dt * 16 + lr;
#pragma unroll
      for (int g = 0; g < 4; ++g) {
        int row = b * S_LEN + i0 + w * 16 + lg * 4 + g;
        out[(size_t)row * 1024 + col] = f2bf(o_acc[dt][g] / ll[g]);
      }
    }
  }
}

extern "C" void kernel_launch(void* const* d_in, const int* in_sizes, int n_in,
                              void* d_out, int out_size, void* d_ws, size_t ws_size,
                              hipStream_t stream) {
  const float* x    = (const float*)d_in[0];
  const float* Wqkv = (const float*)d_in[1];
  const float* Wout = (const float*)d_in[2];
  const float* Wpos = (const float*)d_in[3];
  const float* u    = (const float*)d_in[4];
  const float* v    = (const float*)d_in[5];
  const float* rel  = (const float*)d_in[6];
  float* out = (float*)d_out;

  u16* ws      = (u16*)d_ws;
  u16* xb      = ws;                      // 4096x1024
  u16* wqkvb   = xb + 4194304;            // 3072x1024
  u16* woutb   = wqkvb + 3145728;         // 1024x1024
  u16* wposb   = woutb + 1048576;         // 1024x1024
  u16* relb    = wposb + 1048576;         // 1024x1024
  u16* qkvb    = relb + 1048576;          // 4096x3072 (k,v parts used)
  u16* qcb     = qkvb + 12582912;         // 4096x1024
  u16* qpb     = qcb + 4194304;           // 4096x1024
  u16* relproj = qpb + 4194304;           // 1024x1024
  u16* attno   = relproj + 1048576;       // 4096x1024

  cvt_all<<<10240, 256, 0, stream>>>(x, Wqkv, Wout, Wpos, rel, xb, wqkvb, woutb, wposb, relb);

  gemm_bt<2, 1, 0><<<dim3(32, 24), 256, 0, stream>>>(xb, wqkvb, nullptr, qkvb, qcb, qpb, u, v, 4096, 3072, 1024);
  gemm_bt<0, 0, 1><<<dim3(16, 8), 256, 0, stream>>>(relb, wposb, nullptr, relproj, nullptr, nullptr, nullptr, nullptr, 1024, 1024, 1024);
  attn_fwd<<<dim3(8, 64), 256, 0, stream>>>(qcb, qpb, qkvb, relproj, attno);
  gemm_bt<1, 0, 1><<<dim3(64, 8), 256, 0, stream>>>(attno, woutb, out, nullptr, nullptr, nullptr, nullptr, nullptr, 4096, 1024, 1024);
}

// Round 7
// 138.604 us; speedup vs baseline: 1.7173x; 1.0899x over previous
//
#include <hip/hip_runtime.h>

#define S_LEN 1024

typedef unsigned short u16;
using bf16x8 = __attribute__((ext_vector_type(8))) short;
using f32x4  = __attribute__((ext_vector_type(4))) float;
using u16x8  = __attribute__((ext_vector_type(8))) unsigned short;
using u16x4  = __attribute__((ext_vector_type(4))) unsigned short;

__device__ __forceinline__ float bf2f(u16 b) {
  unsigned int u = ((unsigned int)b) << 16;
  return __builtin_bit_cast(float, u);
}
__device__ __forceinline__ u16 f2bf(float f) {
  unsigned int u = __builtin_bit_cast(unsigned int, f);
  unsigned int r = u + 0x7fffu + ((u >> 16) & 1u);
  return (u16)(r >> 16);
}

using gas_p = const __attribute__((address_space(1))) void*;
using las_p = __attribute__((address_space(3))) void*;
__device__ __forceinline__ void gload16(const void* g, void* l) {
  __builtin_amdgcn_global_load_lds((gas_p)g, (las_p)l, 16, 0, 0);
}

// ---------------- merged f32 -> bf16 conversion ----------------
__global__ __launch_bounds__(256) void cvt_all(const float* __restrict__ x,
    const float* __restrict__ wqkv, const float* __restrict__ wout,
    const float* __restrict__ wpos, const float* __restrict__ rel,
    u16* __restrict__ xb, u16* __restrict__ wqkvb, u16* __restrict__ woutb,
    u16* __restrict__ wposb, u16* __restrict__ relb) {
  int blk = blockIdx.x;
  const float* src; u16* dst; int base;
  if (blk < 4096)      { src = x;    dst = xb;    base = blk; }
  else if (blk < 7168) { src = wqkv; dst = wqkvb; base = blk - 4096; }
  else if (blk < 8192) { src = wout; dst = woutb; base = blk - 7168; }
  else if (blk < 9216) { src = wpos; dst = wposb; base = blk - 8192; }
  else                 { src = rel;  dst = relb;  base = blk - 9216; }
  int i = (base * 256 + threadIdx.x) * 4;
  float4 v = *(const float4*)(src + i);
  u16x4 o;
  o.x = f2bf(v.x); o.y = f2bf(v.y); o.z = f2bf(v.z); o.w = f2bf(v.w);
  *(u16x4*)(dst + i) = o;
}

// ---------------- GEMM: Y = A @ W^T (double-buffered, stage-ahead) ----------------
// MODE 0: bf16 out. MODE 1: f32 out.
// MODE 2: qkv-fused: q cols -> qc=(q+u)/8, qp=(q+v)/8; k cols -> Yb cols 1024..2047;
//         v cols -> TRANSPOSED into the unused q-column hole of Yb:
//         V^T[bh*64+d][s] at Yb[(b*1024 + h*64 + d)*3072 + s]  (cols 0..1023).
// SWZ: 1 = XCD swizzle for grid(32,24). BM64: 64-row A tile.
template <int MODE, int SWZ, int BM64>
__global__ __launch_bounds__(256) void gemm_bt(const u16* __restrict__ A,
    const u16* __restrict__ W, float* __restrict__ Yf, u16* __restrict__ Yb,
    u16* __restrict__ qc, u16* __restrict__ qp,
    const float* __restrict__ uvec, const float* __restrict__ vvec,
    int M, int N, int K) {
  constexpr int BM = BM64 ? 64 : 128;
  constexpr int MI = BM64 ? 2 : 4;
  __shared__ __align__(16) u16 As[2][BM * 32];
  __shared__ __align__(16) u16 Ws[2][128 * 32];
  const int t = threadIdx.x;
  const int w = t >> 6, l = t & 63;
  const int lr = l & 15, lg = l >> 4;
  int bm, bn;
  if (SWZ == 1) {
    int flat = (int)blockIdx.y * 32 + (int)blockIdx.x;
    int xcd = flat & 7, idx = flat >> 3;
    bm = (xcd & 3) * 8 + (idx & 7);
    bn = (xcd >> 2) * 12 + (idx >> 3);
  } else {
    bm = blockIdx.x; bn = blockIdx.y;
  }
  const int wr = BM64 ? ((w >> 1) * 32) : ((w >> 1) * 64);
  const int wc = (w & 1) * 64;
  f32x4 acc[MI][4];
#pragma unroll
  for (int mi = 0; mi < MI; ++mi)
#pragma unroll
    for (int ni = 0; ni < 4; ++ni) acc[mi][ni] = (f32x4){0.f, 0.f, 0.f, 0.f};
  const u16* Ab = A + (size_t)bm * BM * K;
  const u16* Wb = W + (size_t)bn * 128 * K;

  auto stage = [&](int k0, int buf) {
#pragma unroll
    for (int i = 0; i < (BM64 ? 1 : 2); ++i) {
      int c = i * 256 + t;
      gload16(Ab + (size_t)(c >> 2) * K + k0 + (c & 3) * 8, &As[buf][c * 8]);
    }
#pragma unroll
    for (int i = 0; i < 2; ++i) {
      int c = i * 256 + t;
      gload16(Wb + (size_t)(c >> 2) * K + k0 + (c & 3) * 8, &Ws[buf][c * 8]);
    }
  };

  stage(0, 0);
  __syncthreads();
  for (int k0 = 0; k0 < K; k0 += 32) {
    const int cur = (k0 >> 5) & 1;
    if (k0 + 32 < K) stage(k0 + 32, cur ^ 1);  // overlaps compute below
    bf16x8 af[MI], wf[4];
#pragma unroll
    for (int mi = 0; mi < MI; ++mi)
      af[mi] = *(const bf16x8*)&As[cur][(wr + mi * 16 + lr) * 32 + lg * 8];
#pragma unroll
    for (int ni = 0; ni < 4; ++ni)
      wf[ni] = *(const bf16x8*)&Ws[cur][(wc + ni * 16 + lr) * 32 + lg * 8];
    __builtin_amdgcn_s_setprio(1);
#pragma unroll
    for (int mi = 0; mi < MI; ++mi)
#pragma unroll
      for (int ni = 0; ni < 4; ++ni)
        acc[mi][ni] = __builtin_amdgcn_mfma_f32_16x16x32_bf16(af[mi], wf[ni], acc[mi][ni], 0, 0, 0);
    __builtin_amdgcn_s_setprio(0);
    __syncthreads();
  }
#pragma unroll
  for (int mi = 0; mi < MI; ++mi)
#pragma unroll
    for (int ni = 0; ni < 4; ++ni) {
      int col = bn * 128 + wc + ni * 16 + lr;
      if (MODE == 1) {
#pragma unroll
        for (int g = 0; g < 4; ++g) {
          int row = bm * BM + wr + mi * 16 + lg * 4 + g;
          Yf[(size_t)row * N + col] = acc[mi][ni][g];
        }
      } else if (MODE == 0) {
#pragma unroll
        for (int g = 0; g < 4; ++g) {
          int row = bm * BM + wr + mi * 16 + lg * 4 + g;
          Yb[(size_t)row * N + col] = f2bf(acc[mi][ni][g]);
        }
      } else {
        if (col < 1024) {
          float uu = uvec[col], vv = vvec[col];
#pragma unroll
          for (int g = 0; g < 4; ++g) {
            int row = bm * BM + wr + mi * 16 + lg * 4 + g;
            qc[(size_t)row * 1024 + col] = f2bf((acc[mi][ni][g] + uu) * 0.125f);
            qp[(size_t)row * 1024 + col] = f2bf((acc[mi][ni][g] + vv) * 0.125f);
          }
        } else if (col < 2048) {
#pragma unroll
          for (int g = 0; g < 4; ++g) {
            int row = bm * BM + wr + mi * 16 + lg * 4 + g;
            Yb[(size_t)row * 3072 + col] = f2bf(acc[mi][ni][g]);
          }
        } else {
          // v-part: write V^T into the q-column hole (cols 0..1023)
          int row0 = bm * BM + wr + mi * 16 + lg * 4;  // 4-aligned, no 1024-crossing
          int vrow = (row0 >> 10) * 1024 + (col - 2048);  // b*1024 + h*64 + d
          u16x4 tmp;
#pragma unroll
          for (int g = 0; g < 4; ++g) tmp[g] = f2bf(acc[mi][ni][g]);
          *(u16x4*)&Yb[(size_t)vrow * 3072 + (row0 & 1023)] = tmp;
        }
      }
    }
}

// ---------------- fused causal attention with TXL rel-shift (v5) ----------------
// Balanced qt-pairs {15-sub, sub} (17 k-tiles/block), f32 score LDS roundtrip,
// A-frag-side softmax, 3-slot sliding R band, frag-block K/V LDS.
// v5: V is pre-transposed globally (QKV epilogue) -> V staging is gload16
// straight into frag-blocks, identical to K staging. No LDS transpose at all.
__global__ __launch_bounds__(256) void attn_fwd(
    const u16* __restrict__ qcb, const u16* __restrict__ qpb,
    const u16* __restrict__ qkv, const u16* __restrict__ relp,
    u16* __restrict__ out) {
  __shared__ __align__(16) u16 Ksb[2][4096];     // 8 frag-blocks x 64 lanes x 8
  __shared__ __align__(16) u16 Vtb[2][4096];     // V^T frag-blocks
  __shared__ __align__(16) u16 Rs3[3][4096];     // 3 sliding 64-row chunks
  __shared__ __align__(16) float Psf[4][16][68]; // per-wave f32 scores [q][k]

  const int flat = (int)blockIdx.y * 8 + (int)blockIdx.x;
  const int wg = (flat & 7) * 64 + (flat >> 3);  // XCD-contiguous chunks of 64
  const int sub = wg & 7;
  const int bh = wg >> 3;
  const int b = bh >> 4, h = bh & 15;
  const int t = threadIdx.x;
  const int w = t >> 6, l = t & 63;
  const int lr = l & 15, lg = l >> 4;

  const u16* Kg = qkv + (size_t)b * S_LEN * 3072 + 1024 + h * 64;
  const u16* Vg = qkv + (size_t)bh * 64 * 3072;  // V^T rows in the q-hole
  const u16* Rg = relp + h * 64;

  int gl4[4], cg[4];
#pragma unroll
  for (int g = 0; g < 4; ++g) {
    int ql = lg * 4 + g;
    gl4[g] = (l & 48) | ((lr - ql - 1) & 15);
    cg[g] = (lr > ql) ? 1 : 0;
  }

  for (int half = 0; half < 2; ++half) {
    const int qt = half ? sub : (15 - sub);
    const int i0 = qt * 64;
    const int nt = qt + 1;

    bf16x8 qcf[2], qpf[2];
    {
      size_t qoff = (size_t)(b * S_LEN + i0 + w * 16 + lr) * 1024 + h * 64;
      qcf[0] = *(const bf16x8*)(qcb + qoff + lg * 8);
      qcf[1] = *(const bf16x8*)(qcb + qoff + 32 + lg * 8);
      qpf[0] = *(const bf16x8*)(qpb + qoff + lg * 8);
      qpf[1] = *(const bf16x8*)(qpb + qoff + 32 + lg * 8);
    }

    auto stage_k = [&](int j0s, int buf) {
#pragma unroll
      for (int i = 0; i < 2; ++i) {
        int bK = i * 4 + w;
        int ttk = bK >> 1, kc = bK & 1;
        gload16(Kg + (size_t)(j0s + ttk * 16 + lr) * 3072 + kc * 32 + lg * 8,
                &Ksb[buf][bK * 512 + l * 8]);
      }
    };
    auto stage_v = [&](int j0s, int buf) {
#pragma unroll
      for (int i = 0; i < 2; ++i) {
        int bV = i * 4 + w;
        int dt = bV >> 1, kc = bV & 1;
        gload16(Vg + (size_t)(dt * 16 + lr) * 3072 + j0s + kc * 32 + lg * 8,
                &Vtb[buf][bV * 512 + l * 8]);
      }
    };
    auto stage_rchunk = [&](int Gloc, int slot) {
      int Gg = 15 - qt + Gloc;
#pragma unroll
      for (int i = 0; i < 2; ++i) {
        int bR = i * 4 + w;
        int btc = bR >> 1, kc = bR & 1;
        int r = Gg * 64 + btc * 16 + lr;
        r = r > S_LEN - 1 ? S_LEN - 1 : r;
        gload16(Rg + (size_t)r * 1024 + kc * 32 + lg * 8,
                &Rs3[slot][bR * 512 + l * 8]);
      }
    };

    float m_run = -1e30f, l_run = 0.f;
    f32x4 o_acc[4];
#pragma unroll
    for (int dt = 0; dt < 4; ++dt) o_acc[dt] = (f32x4){0.f, 0.f, 0.f, 0.f};

    stage_k(0, 0);
    stage_v(0, 0);
    stage_rchunk(0, 0);
    stage_rchunk(1, 1);
    __syncthreads();

    int sA = 0, sB = 1, sC = 2;
    for (int kt = 0; kt < nt; ++kt) {
      const int cur = kt & 1, nxt = cur ^ 1;
      const int j0 = kt * 64;
      const int have_nxt = (kt + 1 < nt);
      if (have_nxt) {
        stage_k(j0 + 64, nxt);
        stage_v(j0 + 64, nxt);
        stage_rchunk(kt + 2, sC);
      }

      // ---- Sc = qc @ K^T ----
      f32x4 sc[4];
      __builtin_amdgcn_s_setprio(1);
#pragma unroll
      for (int tt = 0; tt < 4; ++tt) {
        sc[tt] = (f32x4){0.f, 0.f, 0.f, 0.f};
#pragma unroll
        for (int kc = 0; kc < 2; ++kc) {
          bf16x8 kf = *(const bf16x8*)&Ksb[cur][(tt * 2 + kc) * 512 + l * 8];
          sc[tt] = __builtin_amdgcn_mfma_f32_16x16x32_bf16(qcf[kc], kf, sc[tt], 0, 0, 0);
        }
      }
      // ---- Sp band (5 tiles per wave) ----
      f32x4 sp[5];
#pragma unroll
      for (int u5 = 0; u5 < 5; ++u5) {
        int bt = 3 - w + u5;
        const u16* rb = (bt & 4) ? &Rs3[sB][0] : &Rs3[sA][0];
        int btc = bt & 3;
        sp[u5] = (f32x4){0.f, 0.f, 0.f, 0.f};
#pragma unroll
        for (int kc = 0; kc < 2; ++kc) {
          bf16x8 rf = *(const bf16x8*)&rb[(btc * 2 + kc) * 512 + l * 8];
          sp[u5] = __builtin_amdgcn_mfma_f32_16x16x32_bf16(qpf[kc], rf, sp[u5], 0, 0, 0);
        }
      }
      __builtin_amdgcn_s_setprio(0);

      // ---- band gather (shfl), add, causal mask, f32 scores -> LDS ----
#pragma unroll
      for (int g = 0; g < 4; ++g) {
        float bp[5];
#pragma unroll
        for (int u5 = 0; u5 < 5; ++u5) bp[u5] = __shfl(sp[u5][g], gl4[g]);
        int ql = lg * 4 + g;
#pragma unroll
        for (int tt = 0; tt < 4; ++tt) {
          float band = cg[g] ? bp[tt + 1] : bp[tt];
          float z = sc[tt][g] + band;
          if (j0 + tt * 16 + lr > i0 + w * 16 + ql) z = -1e30f;
          Psf[w][ql][tt * 16 + lr] = z;
        }
      }

      // ---- A-frag-side softmax ----
      float zz[2][8];
#pragma unroll
      for (int kc = 0; kc < 2; ++kc)
#pragma unroll
        for (int h4 = 0; h4 < 2; ++h4) {
          float4 rr = *(const float4*)&Psf[w][lr][kc * 32 + lg * 8 + h4 * 4];
          zz[kc][h4 * 4 + 0] = rr.x; zz[kc][h4 * 4 + 1] = rr.y;
          zz[kc][h4 * 4 + 2] = rr.z; zz[kc][h4 * 4 + 3] = rr.w;
        }
      float mt = zz[0][0];
#pragma unroll
      for (int kc = 0; kc < 2; ++kc)
#pragma unroll
        for (int j = 0; j < 8; ++j) mt = fmaxf(mt, zz[kc][j]);
      mt = fmaxf(mt, __shfl_xor(mt, 16));
      mt = fmaxf(mt, __shfl_xor(mt, 32));
      float mnew = fmaxf(m_run, mt);
      float corr = __expf(m_run - mnew);
      m_run = mnew;
      float s = 0.f;
#pragma unroll
      for (int kc = 0; kc < 2; ++kc)
#pragma unroll
        for (int j = 0; j < 8; ++j) {
          float e = __expf(zz[kc][j] - mnew);
          zz[kc][j] = e;
          s += e;
        }
      s += __shfl_xor(s, 16);
      s += __shfl_xor(s, 32);
      l_run = l_run * corr + s;

      float co[4];
#pragma unroll
      for (int g = 0; g < 4; ++g) co[g] = __shfl(corr, lg * 4 + g);
#pragma unroll
      for (int dt = 0; dt < 4; ++dt)
#pragma unroll
        for (int g = 0; g < 4; ++g) o_acc[dt][g] *= co[g];

      bf16x8 pf[2];
#pragma unroll
      for (int kc = 0; kc < 2; ++kc)
#pragma unroll
        for (int j = 0; j < 8; ++j) pf[kc][j] = (short)f2bf(zz[kc][j]);

      // ---- O += P @ V ----
      __builtin_amdgcn_s_setprio(1);
#pragma unroll
      for (int dt = 0; dt < 4; ++dt) {
#pragma unroll
        for (int kc = 0; kc < 2; ++kc) {
          bf16x8 vf = *(const bf16x8*)&Vtb[cur][(dt * 2 + kc) * 512 + l * 8];
          o_acc[dt] = __builtin_amdgcn_mfma_f32_16x16x32_bf16(pf[kc], vf, o_acc[dt], 0, 0, 0);
        }
      }
      __builtin_amdgcn_s_setprio(0);
      __syncthreads();
      int stmp = sA; sA = sB; sB = sC; sC = stmp;
    }

    float ll[4];
#pragma unroll
    for (int g = 0; g < 4; ++g) ll[g] = __shfl(l_run, lg * 4 + g);
#pragma unroll
    for (int dt = 0; dt < 4; ++dt) {
      int col = h * 64 + dt * 16 + lr;
#pragma unroll
      for (int g = 0; g < 4; ++g) {
        int row = b * S_LEN + i0 + w * 16 + lg * 4 + g;
        out[(size_t)row * 1024 + col] = f2bf(o_acc[dt][g] / ll[g]);
      }
    }
  }
}

extern "C" void kernel_launch(void* const* d_in, const int* in_sizes, int n_in,
                              void* d_out, int out_size, void* d_ws, size_t ws_size,
                              hipStream_t stream) {
  const float* x    = (const float*)d_in[0];
  const float* Wqkv = (const float*)d_in[1];
  const float* Wout = (const float*)d_in[2];
  const float* Wpos = (const float*)d_in[3];
  const float* u    = (const float*)d_in[4];
  const float* v    = (const float*)d_in[5];
  const float* rel  = (const float*)d_in[6];
  float* out = (float*)d_out;

  u16* ws      = (u16*)d_ws;
  u16* xb      = ws;                      // 4096x1024
  u16* wqkvb   = xb + 4194304;            // 3072x1024
  u16* woutb   = wqkvb + 3145728;         // 1024x1024
  u16* wposb   = woutb + 1048576;         // 1024x1024
  u16* relb    = wposb + 1048576;         // 1024x1024
  u16* qkvb    = relb + 1048576;          // 4096x3072: cols 0-1023 = V^T, 1024-2047 = K
  u16* qcb     = qkvb + 12582912;         // 4096x1024
  u16* qpb     = qcb + 4194304;           // 4096x1024
  u16* relproj = qpb + 4194304;           // 1024x1024
  u16* attno   = relproj + 1048576;       // 4096x1024

  cvt_all<<<10240, 256, 0, stream>>>(x, Wqkv, Wout, Wpos, rel, xb, wqkvb, woutb, wposb, relb);

  gemm_bt<2, 1, 0><<<dim3(32, 24), 256, 0, stream>>>(xb, wqkvb, nullptr, qkvb, qcb, qpb, u, v, 4096, 3072, 1024);
  gemm_bt<0, 0, 1><<<dim3(16, 8), 256, 0, stream>>>(relb, wposb, nullptr, relproj, nullptr, nullptr, nullptr, nullptr, 1024, 1024, 1024);
  attn_fwd<<<dim3(8, 64), 256, 0, stream>>>(qcb, qpb, qkvb, relproj, attno);
  gemm_bt<1, 0, 1><<<dim3(64, 8), 256, 0, stream>>>(attno, woutb, out, nullptr, nullptr, nullptr, nullptr, nullptr, 4096, 1024, 1024);
}